// Round 6
// baseline (24.932 us; speedup 1.0000x reference)
//
#include <hip/hip_runtime.h>
#include <hip/hip_bf16.h>

#define BB 8
#define NN 256
#define DD 64
#define HH 8
#define PP 4

typedef __attribute__((ext_vector_type(8))) short bf16x8;
typedef __attribute__((ext_vector_type(4))) float f32x4;
typedef __attribute__((ext_vector_type(4))) int i32x4;

// HW bf16 convert (RNE): compiler fuses float->__bf16 pairs into v_cvt_pk_bf16_f32
static __device__ __forceinline__ unsigned pack2(float lo, float hi) {
  __bf16 a = (__bf16)lo, b = (__bf16)hi;
  unsigned short ua = __builtin_bit_cast(unsigned short, a);
  unsigned short ub = __builtin_bit_cast(unsigned short, b);
  return (unsigned)ua | ((unsigned)ub << 16);
}

static __device__ __forceinline__ bf16x8 pack8(float4 a, float4 b) {
  union { bf16x8 v; unsigned u[4]; } r;
  r.u[0] = pack2(a.x, a.y); r.u[1] = pack2(a.z, a.w);
  r.u[2] = pack2(b.x, b.y); r.u[3] = pack2(b.z, b.w);
  return r.v;
}

// LDS fragment address: fidx in [0,48), lane in [0,64), 16B units.
// XOR swizzle spreads bank-quads on the write side; read side is a
// permutation within each 128B row (contiguous-1KB wave read stays conflict-free).
static __device__ __forceinline__ int frag_addr(int fidx, int lane) {
  return ((fidx * 64 + lane) * 16) ^ ((((lane >> 3) ^ fidx) & 7) << 4);
}

// Fused: Z = conv-row-factor in LDS (bf16 MFMA B-frag layout), then
// out[b,h,i,j] = (sum_ki sum_d x[b,i+ki-1,d]*Z[h,ki,j,d] + conv_b[h]) * (edge[b,i,j,:].edge_w[h,:])
// Tile: 32i x 32j x 4 heads per block; 4 waves = (rowq x jh) quadrants.
// Grid = 8b * 8it * 8jt * 2hh = 1024 -> 3 blocks/CU (48KB LDS), 12 waves/CU.
// Chunked XCD swizzle: each XCD owns one batch b (whole working set L2-resident).
__global__ __launch_bounds__(256, 3)
void fused_kernel(const float* __restrict__ x, const float* __restrict__ edge,
                  const float* __restrict__ conv_w, const float* __restrict__ conv_b,
                  const float* __restrict__ edge_w, float* __restrict__ out) {
  __shared__ bf16x8 frag_s[48 * 64];     // 49152 B
  char* fragb = (char*)frag_s;

  const int p   = blockIdx.x;
  const int lid = (p & 7) * 128 + (p >> 3);   // XCD c gets lids [c*128,(c+1)*128) = batch c
  const int hh = lid & 1;
  const int jt = (lid >> 1) & 7;
  const int it = (lid >> 4) & 7;
  const int b  = lid >> 7;
  const int h0 = hh * 4;
  const int i0 = it * 32;
  const int j0 = jt * 32;

  const int tid  = threadIdx.x;
  const int lane = tid & 63;
  const int wave = tid >> 6;
  const int lrow = lane & 15;            // i within 16-group / j-col of B frag
  const int lkk  = lane >> 4;            // k-octet / D row-quad (j)
  const int rowq = wave >> 1;            // which 16-row group
  const int jh   = wave & 1;             // which 16-col group
  const int iw = i0 + rowq * 16;
  const int jw = j0 + jh * 16;

  // ---- Z phase: wave = head (h0+wave); thread (zo,zjq) = (d-octet, j-quartet).
  // Z[h,ki,j,d] = sum_kj conv_w[h,d,ki,kj] * x[b,j+kj-1,d], written as MFMA B-frags.
  {
    const int zh  = wave;                // head within block
    const int zo  = lane >> 3;           // d-octet 0..7
    const int zjq = lane & 7;            // j-quartet 0..7 (32 cols)
    const int zd0 = zo * 8;
    const int jq0 = j0 + zjq * 4;

    float xv[6][8];
#pragma unroll
    for (int m = 0; m < 6; ++m) {
      int jg = jq0 - 1 + m;
      if (jg >= 0 && jg < NN) {
        const float* px = x + ((size_t)(b * NN + jg)) * DD + zd0;
        float4 f0 = *(const float4*)(px);
        float4 f1 = *(const float4*)(px + 4);
        xv[m][0] = f0.x; xv[m][1] = f0.y; xv[m][2] = f0.z; xv[m][3] = f0.w;
        xv[m][4] = f1.x; xv[m][5] = f1.y; xv[m][6] = f1.z; xv[m][7] = f1.w;
      } else {
#pragma unroll
        for (int e = 0; e < 8; ++e) xv[m][e] = 0.f;
      }
    }

    i32x4 vv[3][4];
#pragma unroll
    for (int ep = 0; ep < 4; ++ep) {
      float w2[18];   // conv_w rows for e = 2*ep, 2*ep+1 (9 floats each, contiguous)
      __builtin_memcpy(w2, conv_w + (size_t)((h0 + zh) * DD + zd0 + 2 * ep) * 9,
                       18 * sizeof(float));
#pragma unroll
      for (int ki = 0; ki < 3; ++ki) {
#pragma unroll
        for (int jj = 0; jj < 4; ++jj) {
          float s0 = w2[ki * 3 + 0] * xv[jj + 0][2 * ep] +
                     w2[ki * 3 + 1] * xv[jj + 1][2 * ep] +
                     w2[ki * 3 + 2] * xv[jj + 2][2 * ep];
          float s1 = w2[9 + ki * 3 + 0] * xv[jj + 0][2 * ep + 1] +
                     w2[9 + ki * 3 + 1] * xv[jj + 1][2 * ep + 1] +
                     w2[9 + ki * 3 + 2] * xv[jj + 2][2 * ep + 1];
          vv[ki][jj][ep] = (int)pack2(s0, s1);
        }
      }
    }

#pragma unroll
    for (int ki = 0; ki < 3; ++ki) {
      int fidx = (((zh * 3 + ki) * 2 + (zo >> 2)) << 1) + (zjq >> 2);
#pragma unroll
      for (int jj = 0; jj < 4; ++jj) {
        int lw = (zo & 3) * 16 + (zjq & 3) * 4 + jj;
        *(i32x4*)(fragb + frag_addr(fidx, lw)) = vv[ki][jj];
      }
    }
  }

  // ---- A fragments: x rows iw-1..iw+16 (SAME padding), fp32->bf16 ----
  bf16x8 a[3][2];
#pragma unroll
  for (int ki = 0; ki < 3; ++ki) {
    int r = iw + lrow + ki - 1;
    bool ok = (r >= 0) && (r < NN);
#pragma unroll
    for (int dh = 0; dh < 2; ++dh) {
      bf16x8 v = {0, 0, 0, 0, 0, 0, 0, 0};
      if (ok) {
        const float* px = x + ((size_t)(b * NN + r)) * DD + dh * 32 + lkk * 8;
        float4 f0 = *(const float4*)(px);
        float4 f1 = *(const float4*)(px + 4);
        v = pack8(f0, f1);
      }
      a[ki][dh] = v;
    }
  }

  __syncthreads();

  // ---- edge loads (L2-resident per XCD; overlap with MFMA below) ----
  float4 e4[4];
  {
    const float* pe = edge + ((size_t)(b * NN + (iw + lrow)) * NN + (jw + lkk * 4)) * PP;
#pragma unroll
    for (int r = 0; r < 4; ++r) e4[r] = *(const float4*)(pe + r * PP);
  }

  // ---- MFMA: 4 heads x 3 ki x 2 dh = 24 per wave, D^T (lane -> one i, 4 j) ----
  f32x4 acc[4];
#pragma unroll
  for (int h = 0; h < 4; ++h) acc[h] = (f32x4){0.f, 0.f, 0.f, 0.f};

#pragma unroll
  for (int h = 0; h < 4; ++h) {
#pragma unroll
    for (int ki = 0; ki < 3; ++ki) {
#pragma unroll
      for (int dh = 0; dh < 2; ++dh) {
        int fidx = (((h * 3 + ki) * 2 + dh) << 1) + jh;
        bf16x8 bz = *(const bf16x8*)(fragb + frag_addr(fidx, lane));
        acc[h] = __builtin_amdgcn_mfma_f32_16x16x32_bf16(bz, a[ki][dh], acc[h], 0, 0, 0);
      }
    }
  }

  // ---- epilogue: edge projection + scale + vectorized (128B-line) store ----
  float4 ew[4];
  float  cb[4];
#pragma unroll
  for (int h = 0; h < 4; ++h) {
    ew[h] = *(const float4*)(edge_w + (h0 + h) * PP);
    cb[h] = conv_b[h0 + h];
  }

  const int i = iw + lrow;
#pragma unroll
  for (int h = 0; h < 4; ++h) {
    f32x4 o;
#pragma unroll
    for (int r = 0; r < 4; ++r) {
      float eh = e4[r].x * ew[h].x + e4[r].y * ew[h].y +
                 e4[r].z * ew[h].z + e4[r].w * ew[h].w;
      o[r] = (acc[h][r] + cb[h]) * eh;
    }
    *(f32x4*)(out + ((size_t)(b * HH + h0 + h) * NN + i) * NN + jw + lkk * 4) = o;
  }
}

extern "C" void kernel_launch(void* const* d_in, const int* in_sizes, int n_in,
                              void* d_out, int out_size, void* d_ws, size_t ws_size,
                              hipStream_t stream) {
  const float* x      = (const float*)d_in[0];
  const float* edge   = (const float*)d_in[1];
  const float* conv_w = (const float*)d_in[2];
  const float* conv_b = (const float*)d_in[3];
  const float* edge_w = (const float*)d_in[4];
  float* out = (float*)d_out;

  fused_kernel<<<BB * 8 * 8 * 2, 256, 0, stream>>>(x, edge, conv_w, conv_b, edge_w, out);
}

// Round 7
// 23.259 us; speedup vs baseline: 1.0719x; 1.0719x over previous
//
#include <hip/hip_runtime.h>
#include <hip/hip_bf16.h>

#define BB 8
#define NN 256
#define DD 64
#define HH 8
#define PP 4

typedef __attribute__((ext_vector_type(8))) short bf16x8;
typedef __attribute__((ext_vector_type(4))) float f32x4;
typedef __attribute__((ext_vector_type(4))) int i32x4;

// HW bf16 convert (RNE): compiler fuses float->__bf16 pairs into v_cvt_pk_bf16_f32
static __device__ __forceinline__ unsigned pack2(float lo, float hi) {
  __bf16 a = (__bf16)lo, b = (__bf16)hi;
  unsigned short ua = __builtin_bit_cast(unsigned short, a);
  unsigned short ub = __builtin_bit_cast(unsigned short, b);
  return (unsigned)ua | ((unsigned)ub << 16);
}

static __device__ __forceinline__ bf16x8 pack8(float4 a, float4 b) {
  union { bf16x8 v; unsigned u[4]; } r;
  r.u[0] = pack2(a.x, a.y); r.u[1] = pack2(a.z, a.w);
  r.u[2] = pack2(b.x, b.y); r.u[3] = pack2(b.z, b.w);
  return r.v;
}

// LDS fragment address: fidx in [0,48), lane-slot in [0,64), 16B units.
// XOR swizzle spreads the write side; read side is a permutation within each
// 128B row (contiguous-1KB wave read stays conflict-free).
static __device__ __forceinline__ int frag_addr(int fidx, int lane) {
  return ((fidx * 64 + lane) * 16) ^ ((((lane >> 3) ^ fidx) & 7) << 4);
}

// Fused: Z = conv-row-factor in LDS (bf16 MFMA B-frag layout), then
// out[b,h,i,j] = (sum_ki sum_d x[b,i+ki-1,d]*Z[h,ki,j,d] + conv_b[h]) * (edge[b,i,j,:].edge_w[h,:])
// Tile: 64i x 16j x 8 heads per block (= R5). 512-thread blocks: 8 waves as
// (rowq 0..3 x head-half 0..1). Grid = 8b*4it*16jt = 512 -> 2 blocks/CU,
// 16 waves/CU = 4 waves/SIMD (2x the 256-thread version, same total work).
__global__ __launch_bounds__(512, 4)
void fused_kernel(const float* __restrict__ x, const float* __restrict__ edge,
                  const float* __restrict__ conv_w, const float* __restrict__ conv_b,
                  const float* __restrict__ edge_w, float* __restrict__ out) {
  __shared__ bf16x8 frag_s[48 * 64];     // 49152 B
  char* fragb = (char*)frag_s;

  const int bid = blockIdx.x;
  const int jt = bid & 15;
  const int it = (bid >> 4) & 3;
  const int b  = bid >> 6;
  const int j0 = jt * 16;
  const int tid  = threadIdx.x;
  const int lane = tid & 63;
  const int wave = tid >> 6;             // 0..7
  const int rowq = wave >> 1;            // 16-row group within the 64-row tile
  const int hh   = wave & 1;             // head half
  const int h0   = hh * 4;
  const int iw   = it * 64 + rowq * 16;
  const int lrow = lane & 15;            // i within 16-group / j col of B frag
  const int lkk  = lane >> 4;            // k-octet / D^T row-quad (j)

  // ---- Z phase: wave w computes head w's frags; lane -> (d-octet zo, j-pair zj).
  // Z[h,ki,j,d] = sum_kj conv_w[h,d,ki,kj] * x[b,j+kj-1,d], written as MFMA B-frags.
  {
    const int zh  = wave;                // head 0..7
    const int zo  = lane >> 3;           // d-octet 0..7
    const int zj  = lane & 7;            // j-pair 0..7 (16 cols)
    const int zd0 = zo * 8;
    const int jq0 = j0 + zj * 2;

    float xv[4][8];                      // x rows jq0-1 .. jq0+2, d = zd0..zd0+7
#pragma unroll
    for (int m = 0; m < 4; ++m) {
      int jg = jq0 - 1 + m;
      if (jg >= 0 && jg < NN) {
        const float* px = x + ((size_t)(b * NN + jg)) * DD + zd0;
        float4 f0 = *(const float4*)(px);
        float4 f1 = *(const float4*)(px + 4);
        xv[m][0] = f0.x; xv[m][1] = f0.y; xv[m][2] = f0.z; xv[m][3] = f0.w;
        xv[m][4] = f1.x; xv[m][5] = f1.y; xv[m][6] = f1.z; xv[m][7] = f1.w;
      } else {
#pragma unroll
        for (int e = 0; e < 8; ++e) xv[m][e] = 0.f;
      }
    }

    i32x4 vv[3][2];
#pragma unroll
    for (int ep = 0; ep < 4; ++ep) {
      float w2[18];   // conv_w rows for e = 2*ep, 2*ep+1 (9 floats each, contiguous)
      __builtin_memcpy(w2, conv_w + (size_t)(zh * DD + zd0 + 2 * ep) * 9,
                       18 * sizeof(float));
#pragma unroll
      for (int ki = 0; ki < 3; ++ki) {
#pragma unroll
        for (int jj = 0; jj < 2; ++jj) {
          float s0 = w2[ki * 3 + 0] * xv[jj + 0][2 * ep] +
                     w2[ki * 3 + 1] * xv[jj + 1][2 * ep] +
                     w2[ki * 3 + 2] * xv[jj + 2][2 * ep];
          float s1 = w2[9 + ki * 3 + 0] * xv[jj + 0][2 * ep + 1] +
                     w2[9 + ki * 3 + 1] * xv[jj + 1][2 * ep + 1] +
                     w2[9 + ki * 3 + 2] * xv[jj + 2][2 * ep + 1];
          vv[ki][jj][ep] = (int)pack2(s0, s1);
        }
      }
    }

#pragma unroll
    for (int ki = 0; ki < 3; ++ki) {
      int fidx = (zh * 3 + ki) * 2 + (zo >> 2);
#pragma unroll
      for (int jj = 0; jj < 2; ++jj) {
        int lw = (zo & 3) * 16 + zj * 2 + jj;
        *(i32x4*)(fragb + frag_addr(fidx, lw)) = vv[ki][jj];
      }
    }
  }

  // ---- A fragments: x rows iw-1..iw+16 (SAME padding), fp32->bf16 ----
  bf16x8 a[3][2];
#pragma unroll
  for (int ki = 0; ki < 3; ++ki) {
    int r = iw + lrow + ki - 1;
    bool ok = (r >= 0) && (r < NN);
#pragma unroll
    for (int dh = 0; dh < 2; ++dh) {
      bf16x8 v = {0, 0, 0, 0, 0, 0, 0, 0};
      if (ok) {
        const float* px = x + ((size_t)(b * NN + r)) * DD + dh * 32 + lkk * 8;
        float4 f0 = *(const float4*)(px);
        float4 f1 = *(const float4*)(px + 4);
        v = pack8(f0, f1);
      }
      a[ki][dh] = v;
    }
  }

  // ---- edge prefetch: lane owns (i = iw+lrow, j = j0+lkk*4 .. +3); issued before
  // the barrier so HBM latency hides under barrier + MFMA-phase LDS reads ----
  float4 e4[4];
  {
    const float* pe = edge + ((size_t)(b * NN + (iw + lrow)) * NN + (j0 + lkk * 4)) * PP;
#pragma unroll
    for (int r = 0; r < 4; ++r) e4[r] = *(const float4*)(pe + r * PP);
  }

  __syncthreads();

  // ---- MFMA: 4 heads x 3 ki x 2 dh = 24 per wave, operands swapped -> D^T ----
  f32x4 acc[4];
#pragma unroll
  for (int h = 0; h < 4; ++h) acc[h] = (f32x4){0.f, 0.f, 0.f, 0.f};

#pragma unroll
  for (int h = 0; h < 4; ++h) {
#pragma unroll
    for (int ki = 0; ki < 3; ++ki) {
#pragma unroll
      for (int dh = 0; dh < 2; ++dh) {
        int fidx = ((h0 + h) * 3 + ki) * 2 + dh;
        bf16x8 bz = *(const bf16x8*)(fragb + frag_addr(fidx, lane));
        acc[h] = __builtin_amdgcn_mfma_f32_16x16x32_bf16(bz, a[ki][dh], acc[h], 0, 0, 0);
      }
    }
  }

  // ---- epilogue: edge projection + scale + vectorized store ----
  float4 ew[4];
  float  cb[4];
#pragma unroll
  for (int h = 0; h < 4; ++h) {
    ew[h] = *(const float4*)(edge_w + (h0 + h) * PP);
    cb[h] = conv_b[h0 + h];
  }

  const int i = iw + lrow;
#pragma unroll
  for (int h = 0; h < 4; ++h) {
    f32x4 o;
#pragma unroll
    for (int r = 0; r < 4; ++r) {
      float eh = e4[r].x * ew[h].x + e4[r].y * ew[h].y +
                 e4[r].z * ew[h].z + e4[r].w * ew[h].w;
      o[r] = (acc[h][r] + cb[h]) * eh;
    }
    *(f32x4*)(out + ((size_t)(b * HH + h0 + h) * NN + i) * NN + j0 + lkk * 4) = o;
  }
}

extern "C" void kernel_launch(void* const* d_in, const int* in_sizes, int n_in,
                              void* d_out, int out_size, void* d_ws, size_t ws_size,
                              hipStream_t stream) {
  const float* x      = (const float*)d_in[0];
  const float* edge   = (const float*)d_in[1];
  const float* conv_w = (const float*)d_in[2];
  const float* conv_b = (const float*)d_in[3];
  const float* edge_w = (const float*)d_in[4];
  float* out = (float*)d_out;

  fused_kernel<<<BB * 4 * 16, 512, 0, stream>>>(x, edge, conv_w, conv_b, edge_w, out);
}